// Round 4
// baseline (477.451 us; speedup 1.0000x reference)
//
#include <hip/hip_runtime.h>
#include <cstdint>
#include <cstddef>

#define AS1 __attribute__((address_space(1)))
#define AS3 __attribute__((address_space(3)))

using half8  = __attribute__((ext_vector_type(8))) _Float16;
using half4v = __attribute__((ext_vector_type(4))) _Float16;
using half2v = __attribute__((ext_vector_type(2))) _Float16;
using f32x4  = __attribute__((ext_vector_type(4))) float;

// ---------- fused prep kernel ----------
// [0,16384):        x -> fp16 (16.8M elems, 4/thread)
// [16384,19456):    Bt 1536x512 fp16 (rows: q|k|v projection weights)
// [19456,20480):    Wo -> fp16 512x512
// [20480,20496):    twiddles (4096: W_4096^p)
// [20496,20502):    bias concat (1536)
__global__ void prep_all_kernel(const float* __restrict__ x,
                                const float* __restrict__ Wq, const float* __restrict__ Wk,
                                const float* __restrict__ Wv, const float* __restrict__ Wo,
                                const float* __restrict__ bq, const float* __restrict__ bk,
                                const float* __restrict__ bv,
                                _Float16* __restrict__ xh, _Float16* __restrict__ Bt,
                                _Float16* __restrict__ WoH,
                                float2* __restrict__ tw, float* __restrict__ bias) {
    const int bid = blockIdx.x;
    const int tid = threadIdx.x;
    if (bid < 16384) {
        int i = (bid * 256 + tid) * 4;
        float4 v = *(const float4*)(x + i);
        half4v h;
        h[0] = (_Float16)v.x; h[1] = (_Float16)v.y;
        h[2] = (_Float16)v.z; h[3] = (_Float16)v.w;
        *(half4v*)(xh + i) = h;
    } else if (bid < 19456) {
        int i = (bid - 16384) * 256 + tid;      // [0, 1536*512)
        int e = i >> 9, k = i & 511;
        int proj = e >> 9, er = e & 511;
        const float* W = (proj == 0) ? Wq : ((proj == 1) ? Wk : Wv);
        Bt[i] = (_Float16)W[er * 512 + k];
    } else if (bid < 20480) {
        int i = (bid - 19456) * 256 + tid;
        WoH[i] = (_Float16)Wo[i];
    } else if (bid < 20496) {
        int p = (bid - 20480) * 256 + tid;      // 4096
        double th = -2.0 * 3.14159265358979323846 * (double)p / 4096.0;
        tw[p] = make_float2((float)cos(th), (float)sin(th));
    } else {
        int i = (bid - 20496) * 256 + tid;      // 1536
        bias[i] = (i < 512) ? bq[i] : ((i < 1024) ? bk[i - 512] : bv[i - 1024]);
    }
}

// ---------- GEMM: C = A * Bt^T (+bias), fp16, K=512, m97-style ----------
template <int MODE>
__global__ __launch_bounds__(256, 4) void gemm_f16_kernel(
    const _Float16* __restrict__ A, const _Float16* __restrict__ Bt,
    const float* __restrict__ bias,
    _Float16* __restrict__ qT, _Float16* __restrict__ kT,
    _Float16* __restrict__ vout, float* __restrict__ Cout)
{
    constexpr int NBLK  = (MODE == 0) ? 12 : 4;
    constexpr int PERXCD = (MODE == 0) ? 384 : 128;   // blocks per XCD slot
    __shared__ _Float16 As[128 * 32];
    __shared__ _Float16 Bs[128 * 32];

    // XCD-aware swizzle: same-mb blocks (sharing the A-tile) colocate on one XCD's L2.
    const int gi = (blockIdx.x & 7) * PERXCD + (blockIdx.x >> 3);
    const int mb = gi / NBLK;
    const int nb = gi - mb * NBLK;
    const int m0 = mb * 128, n0 = nb * 128;
    const int tid = threadIdx.x;
    const int wave = tid >> 6, lane = tid & 63;
    const int wm = (wave & 1) * 64, wn = (wave >> 1) * 64;
    const int lane15 = lane & 15, quad = lane >> 4;
    const int srow = lane >> 2;
    const int scolB = (lane & 3) * 16;

    f32x4 acc[4][4];
#pragma unroll
    for (int mi = 0; mi < 4; mi++)
#pragma unroll
        for (int ni = 0; ni < 4; ni++)
#pragma unroll
            for (int r = 0; r < 4; r++) acc[mi][ni][r] = 0.f;

    for (int kt = 0; kt < 16; kt++) {
        const int kg = kt * 32;
        __syncthreads();
#pragma unroll
        for (int i = 0; i < 2; i++) {
            const int rb = wave * 32 + i * 16;
            const char* ga = (const char*)A  + ((size_t)(m0 + rb + srow)) * 1024 + kg * 2 + scolB;
            const char* gb = (const char*)Bt + ((size_t)(n0 + rb + srow)) * 1024 + kg * 2 + scolB;
            __builtin_amdgcn_global_load_lds((const AS1 void*)ga, (AS3 void*)((char*)As + rb * 64), 16, 0, 0);
            __builtin_amdgcn_global_load_lds((const AS1 void*)gb, (AS3 void*)((char*)Bs + rb * 64), 16, 0, 0);
        }
        __syncthreads();
        half8 af[4], bfr[4];
#pragma unroll
        for (int mi = 0; mi < 4; mi++)
            af[mi] = *(const half8*)((const char*)As + (wm + mi * 16 + lane15) * 64 + quad * 16);
#pragma unroll
        for (int ni = 0; ni < 4; ni++)
            bfr[ni] = *(const half8*)((const char*)Bs + (wn + ni * 16 + lane15) * 64 + quad * 16);
#pragma unroll
        for (int mi = 0; mi < 4; mi++)
#pragma unroll
            for (int ni = 0; ni < 4; ni++)
                acc[mi][ni] = __builtin_amdgcn_mfma_f32_16x16x32_f16(af[mi], bfr[ni], acc[mi][ni], 0, 0, 0);
    }

    if (MODE == 1) {
#pragma unroll
        for (int mi = 0; mi < 4; mi++)
#pragma unroll
            for (int ni = 0; ni < 4; ni++) {
                const int n = n0 + wn + ni * 16 + lane15;
                const float bb = bias[n];
#pragma unroll
                for (int r = 0; r < 4; r++) {
                    const int m = m0 + wm + mi * 16 + quad * 4 + r;
                    Cout[(size_t)m * 512 + n] = acc[mi][ni][r] + bb;
                }
            }
        return;
    }
    const int proj = n0 >> 9;
    if (proj == 2) {   // V -> fp16 (B,H,L,D)
#pragma unroll
        for (int mi = 0; mi < 4; mi++)
#pragma unroll
            for (int ni = 0; ni < 4; ni++) {
                const int n = n0 + wn + ni * 16 + lane15;
                const int er = n - 1024, h = er >> 6, d = er & 63;
                const float bb = bias[n];
#pragma unroll
                for (int r = 0; r < 4; r++) {
                    const int m = m0 + wm + mi * 16 + quad * 4 + r;
                    const int b = m >> 12, l = m & 4095;
                    vout[((size_t)((b * 8 + h) * 4096 + l)) * 64 + d] = (_Float16)(acc[mi][ni][r] + bb);
                }
            }
        return;
    }
    // Q/K: packed-fp16 transposed stores. Lane holds 4 consecutive l (quad*4+r).
    _Float16* dst = (proj == 0) ? qT : kT;
    const int b = m0 >> 12;
    const int lbase = (m0 & 4095) + wm + quad * 4;
#pragma unroll
    for (int mi = 0; mi < 4; mi++)
#pragma unroll
        for (int ni = 0; ni < 4; ni++) {
            const int e = n0 + wn + ni * 16 + lane15;
            const int er = e & 511, h = er >> 6, d = er & 63;
            const float bb = bias[e];
            half4v o;
            o[0] = (_Float16)(acc[mi][ni][0] + bb);
            o[1] = (_Float16)(acc[mi][ni][1] + bb);
            o[2] = (_Float16)(acc[mi][ni][2] + bb);
            o[3] = (_Float16)(acc[mi][ni][3] + bb);
            *(half4v*)(dst + ((size_t)((b * 8 + h) * 64 + d)) * 4096 + lbase + mi * 16) = o;
        }
}

// ---------- FFT: 4096-pt, radix-16 (in-register DFT-16), in-place 32KB LDS ----------
__device__ __forceinline__ float2 cmul(float2 a, float2 b) {
    return make_float2(a.x * b.x - a.y * b.y, a.x * b.y + a.y * b.x);
}
__device__ __forceinline__ float2 cmulc(float2 a, float cr, float ci) {
    return make_float2(a.x * cr - a.y * ci, a.x * ci + a.y * cr);
}
__device__ __forceinline__ int swz(int i) { return i ^ ((i >> 4) & 15); }

// DFT-16 in registers: two radix-4 DIF layers (s=1 then s=4) with W16 twiddles.
// Output natural order.
__device__ __forceinline__ void dft16(float2 x[16]) {
    // W16^e = (cos(-pi e/8), sin(-pi e/8)); e = u*m, u,m in [0,4)
    constexpr float wc[10] = {1.f, 0.92387953f, 0.70710678f, 0.38268343f, 0.f,
                              0.f, -0.70710678f, 0.f, 0.f, -0.92387953f};
    constexpr float wsn[10] = {0.f, -0.38268343f, -0.70710678f, -0.92387953f, -1.f,
                               0.f, -0.70710678f, 0.f, 0.f, 0.38268343f};
    float2 t[16];
#pragma unroll
    for (int u = 0; u < 4; u++) {
        const float2 a = x[u], b = x[u + 4], c = x[u + 8], d = x[u + 12];
        const float2 Ea = make_float2(a.x + c.x, a.y + c.y);
        const float2 Oa = make_float2(a.x - c.x, a.y - c.y);
        const float2 Eb = make_float2(b.x + d.x, b.y + d.y);
        const float2 Ob = make_float2(b.x - d.x, b.y - d.y);
        const float2 y0 = make_float2(Ea.x + Eb.x, Ea.y + Eb.y);
        const float2 y1 = make_float2(Oa.x + Ob.y, Oa.y - Ob.x);   // Oa - i*Ob
        const float2 y2 = make_float2(Ea.x - Eb.x, Ea.y - Eb.y);
        const float2 y3 = make_float2(Oa.x - Ob.y, Oa.y + Ob.x);   // Oa + i*Ob
        t[4 * u + 0] = y0;
        t[4 * u + 1] = cmulc(y1, wc[u * 1], wsn[u * 1]);
        t[4 * u + 2] = cmulc(y2, wc[u * 2], wsn[u * 2]);
        t[4 * u + 3] = cmulc(y3, wc[u * 3], wsn[u * 3]);
    }
#pragma unroll
    for (int v = 0; v < 4; v++) {
        const float2 a = t[v], b = t[v + 4], c = t[v + 8], d = t[v + 12];
        const float2 Ea = make_float2(a.x + c.x, a.y + c.y);
        const float2 Oa = make_float2(a.x - c.x, a.y - c.y);
        const float2 Eb = make_float2(b.x + d.x, b.y + d.y);
        const float2 Ob = make_float2(b.x - d.x, b.y - d.y);
        x[v]      = make_float2(Ea.x + Eb.x, Ea.y + Eb.y);
        x[v + 4]  = make_float2(Oa.x + Ob.y, Oa.y - Ob.x);
        x[v + 8]  = make_float2(Ea.x - Eb.x, Ea.y - Eb.y);
        x[v + 12] = make_float2(Oa.x - Ob.y, Oa.y + Ob.x);
    }
}

// In-place 4096-pt forward FFT over swizzled buf. Entry sync covers caller's fill;
// exits synced. 3 stages s=1,16,256; twiddle W_4096^{s*p*m} from 4096-entry table.
__device__ __forceinline__ void fft4096_r16(float2* buf, const float2* __restrict__ tw,
                                            int tid) {
    float2 x[16];
    // ---- stage A: s=1, q=0, p=tid ----
    __syncthreads();
#pragma unroll
    for (int j = 0; j < 16; j++) x[j] = buf[swz(tid + 256 * j)];
    __syncthreads();
    dft16(x);
    buf[swz(16 * tid)] = x[0];
#pragma unroll
    for (int m = 1; m < 16; m++) buf[swz(16 * tid + m)] = cmul(x[m], tw[tid * m]);
    __syncthreads();
    // ---- stage B: s=16, q=tid&15, p=tid>>4 ----
#pragma unroll
    for (int j = 0; j < 16; j++) x[j] = buf[swz(tid + 256 * j)];
    __syncthreads();
    dft16(x);
    {
        const int q = tid & 15, p = tid >> 4;
        const int base = q + 256 * p;
        buf[swz(base)] = x[0];
#pragma unroll
        for (int m = 1; m < 16; m++)
            buf[swz(base + 16 * m)] = cmul(x[m], tw[(p * m) << 4]);
    }
    __syncthreads();
    // ---- stage C: s=256, q=tid, p=0 (no twiddle) ----
#pragma unroll
    for (int j = 0; j < 16; j++) x[j] = buf[swz(tid + 256 * j)];
    __syncthreads();
    dft16(x);
#pragma unroll
    for (int m = 0; m < 16; m++) buf[swz(tid + 256 * m)] = x[m];
    __syncthreads();
}

// per block: one (b,h), 4 d's. Packed FFT(q + i k), accumulate S=Q*conj(K), write partial.
__global__ __launch_bounds__(256, 4) void fft_partial_kernel(
    const _Float16* __restrict__ qT, const _Float16* __restrict__ kT,
    const float2* __restrict__ tw, float2* __restrict__ spec)
{
    __shared__ float2 buf[4096];
    const int tid = threadIdx.x;
    const int bh = blockIdx.x >> 4, chunk = blockIdx.x & 15;
    float sx[16], sy[16];
#pragma unroll
    for (int i = 0; i < 16; i++) { sx[i] = 0.f; sy[i] = 0.f; }
    const _Float16* qb = qT + (size_t)bh * 64 * 4096;
    const _Float16* kb = kT + (size_t)bh * 64 * 4096;
    for (int dd = 0; dd < 4; dd++) {
        const int d = chunk * 4 + dd;
#pragma unroll
        for (int i = 0; i < 2; i++) {
            const int t0 = 2048 * i + tid * 8;
            const half8 fq = *(const half8*)(qb + d * 4096 + t0);
            const half8 fk = *(const half8*)(kb + d * 4096 + t0);
#pragma unroll
            for (int j = 0; j < 8; j++)
                buf[swz(t0 + j)] = make_float2((float)fq[j], (float)fk[j]);
        }
        fft4096_r16(buf, tw, tid);
        // unpack packed transforms; accumulate S = Q * conj(K)
#pragma unroll
        for (int i = 0; i < 16; i++) {
            const int f = tid + 256 * i;
            const float2 Zf = buf[swz(f)];
            const float2 Zm = buf[swz((4096 - f) & 4095)];
            const float Qr  = 0.5f * (Zf.x + Zm.x);
            const float Qi  = 0.5f * (Zf.y - Zm.y);
            const float cKr = 0.5f * (Zf.y + Zm.y);
            const float cKi = 0.5f * (Zf.x - Zm.x);
            sx[i] += Qr * cKr - Qi * cKi;
            sy[i] += Qr * cKi + Qi * cKr;
        }
        __syncthreads();   // protect buf before next fill
    }
    float2* out = spec + (size_t)blockIdx.x * 4096;
#pragma unroll
    for (int i = 0; i < 16; i++) out[tid + 256 * i] = make_float2(sx[i], sy[i]);
}

// per block: one (b,h). Sum 16 partials, corr = Re(FFT(conj(S))); top-8 + softmax.
__global__ __launch_bounds__(256) void reduce_topk_kernel(
    const float2* __restrict__ spec, const float2* __restrict__ tw,
    int* __restrict__ top_idx, float* __restrict__ top_w)
{
    __shared__ float2 buf[4096];
    __shared__ float wv[4];
    __shared__ int wi[4];
    const int tid = threadIdx.x;
    const int bh = blockIdx.x;
#pragma unroll
    for (int i = 0; i < 16; i++) {
        const int f = tid + 256 * i;
        float sr = 0.f, si = 0.f;
        for (int c = 0; c < 16; c++) {
            const float2 v = spec[((size_t)(bh * 16 + c)) * 4096 + f];
            sr += v.x; si += v.y;
        }
        buf[swz(f)] = make_float2(sr, -si);   // conj
    }
    fft4096_r16(buf, tw, tid);
    // buf[tau].x ~ corr(tau) (unscaled). Top-8, lower-index tie-break.
    float vals[8]; int idxs[8];
    for (int k = 0; k < 8; k++) {
        float best = -3.0e38f; int bi = 0;
#pragma unroll
        for (int i = 0; i < 16; i++) {
            const int f = tid + 256 * i;
            const float c = buf[swz(f)].x;
            if (c > best) { best = c; bi = f; }
        }
#pragma unroll
        for (int off = 32; off > 0; off >>= 1) {
            const float ov = __shfl_down(best, off);
            const int oi = __shfl_down(bi, off);
            if (ov > best || (ov == best && oi < bi)) { best = ov; bi = oi; }
        }
        if ((tid & 63) == 0) { wv[tid >> 6] = best; wi[tid >> 6] = bi; }
        __syncthreads();
        if (tid == 0) {
            best = wv[0]; bi = wi[0];
            for (int w = 1; w < 4; w++) {
                if (wv[w] > best || (wv[w] == best && wi[w] < bi)) { best = wv[w]; bi = wi[w]; }
            }
            vals[k] = best; idxs[k] = bi;
            buf[swz(bi)].x = -3.4e38f;
        }
        __syncthreads();
    }
    if (tid == 0) {
        const float scale = 1.f / (4096.f * 64.f);
        float e[8], s = 0.f;
        const float mx = vals[0] * scale;
        for (int k = 0; k < 8; k++) { e[k] = __expf(vals[k] * scale - mx); s += e[k]; }
        for (int k = 0; k < 8; k++) {
            top_w[bh * 8 + k] = e[k] / s;
            top_idx[bh * 8 + k] = idxs[k];
        }
    }
}

// ---------- gather: out_pre[b,l,h*64+d] = sum_k w_k * v[b,h,(l+idx_k)%L,d] ----------
__global__ __launch_bounds__(256) void gather_kernel(
    const half2v* __restrict__ v2, const int* __restrict__ top_idx,
    const float* __restrict__ top_w, half2v* __restrict__ out2)
{
    const int seq = blockIdx.x;           // 32768
    const int bh = seq >> 9;
    const int lgrp = seq & 511;
    const int b = bh >> 3, h = bh & 7;
    const int tid = threadIdx.x;
    const int l = lgrp * 8 + (tid >> 5);
    const int d2 = tid & 31;              // half2 index
    int idx[8]; float w[8];
#pragma unroll
    for (int k = 0; k < 8; k++) { idx[k] = top_idx[bh * 8 + k]; w[k] = top_w[bh * 8 + k]; }
    const half2v* vb = v2 + (size_t)bh * 4096 * 32;
    float a0 = 0.f, a1 = 0.f;
#pragma unroll
    for (int k = 0; k < 8; k++) {
        const int ls = (l + idx[k]) & 4095;
        const half2v pv = vb[ls * 32 + d2];
        a0 += w[k] * (float)pv[0];
        a1 += w[k] * (float)pv[1];
    }
    half2v o; o[0] = (_Float16)a0; o[1] = (_Float16)a1;
    out2[((size_t)(b * 4096 + l)) * 256 + h * 32 + d2] = o;
}

// ---------- host ----------
extern "C" void kernel_launch(void* const* d_in, const int* in_sizes, int n_in,
                              void* d_out, int out_size, void* d_ws, size_t ws_size,
                              hipStream_t stream) {
    (void)in_sizes; (void)n_in; (void)out_size; (void)ws_size;
    const float* x  = (const float*)d_in[0];
    const float* Wq = (const float*)d_in[1];
    const float* bq = (const float*)d_in[2];
    const float* Wk = (const float*)d_in[3];
    const float* bk = (const float*)d_in[4];
    const float* Wv = (const float*)d_in[5];
    const float* bv = (const float*)d_in[6];
    const float* Wo = (const float*)d_in[7];
    const float* bo = (const float*)d_in[8];
    float* out = (float*)d_out;

    char* ws = (char*)d_ws;
    size_t off = 0;
    auto alloc = [&](size_t bytes) -> void* {
        void* p = ws + off; off += (bytes + 255) & ~(size_t)255; return p;
    };
    _Float16* xh   = (_Float16*)alloc(33554432);   // 32768x512 fp16
    _Float16* qT   = (_Float16*)alloc(33554432);   // (B,H,D,L) fp16
    _Float16* kT   = (_Float16*)alloc(33554432);
    _Float16* vbuf = (_Float16*)alloc(33554432);   // (B,H,L,D) fp16
    float2* spec   = (float2*)alloc(33554432);     // 1024 x 4096 float2
    _Float16* BtH  = (_Float16*)alloc(1572864);    // 1536x512 fp16
    _Float16* WoH  = (_Float16*)alloc(524288);     // 512x512 fp16
    float* biasQKV = (float*)alloc(6144);          // 1536 fp32
    float2* tw     = (float2*)alloc(32768);        // 4096 twiddles
    int*   top_idx = (int*)alloc(2048);
    float* top_w   = (float*)alloc(2048);
    _Float16* out_pre = xh;                        // alias: xh dead after GEMM1

    prep_all_kernel<<<20502, 256, 0, stream>>>(x, Wq, Wk, Wv, Wo, bq, bk, bv,
                                               xh, BtH, WoH, tw, biasQKV);
    gemm_f16_kernel<0><<<3072, 256, 0, stream>>>(xh, BtH, biasQKV, qT, kT, vbuf, nullptr);
    fft_partial_kernel<<<1024, 256, 0, stream>>>(qT, kT, tw, spec);
    reduce_topk_kernel<<<64, 256, 0, stream>>>(spec, tw, top_idx, top_w);
    gather_kernel<<<32768, 256, 0, stream>>>((const half2v*)vbuf, top_idx, top_w,
                                             (half2v*)out_pre);
    gemm_f16_kernel<1><<<1024, 256, 0, stream>>>(out_pre, WoH, bo, nullptr, nullptr, nullptr, out);
}

// Round 5
// 370.113 us; speedup vs baseline: 1.2900x; 1.2900x over previous
//
#include <hip/hip_runtime.h>
#include <cstdint>
#include <cstddef>

#define AS1 __attribute__((address_space(1)))
#define AS3 __attribute__((address_space(3)))

using half8  = __attribute__((ext_vector_type(8))) _Float16;
using half4v = __attribute__((ext_vector_type(4))) _Float16;
using half2v = __attribute__((ext_vector_type(2))) _Float16;
using f32x4  = __attribute__((ext_vector_type(4))) float;

// ---------- fused prep kernel ----------
// [0,16384):        x -> fp16 (16.8M elems, 4/thread)
// [16384,19456):    Bt 1536x512 fp16 (rows: q|k|v projection weights)
// [19456,20480):    Wo -> fp16 512x512
// [20480,20496):    twiddles (4096: W_4096^p)
// [20496,20502):    bias concat (1536)
__global__ void prep_all_kernel(const float* __restrict__ x,
                                const float* __restrict__ Wq, const float* __restrict__ Wk,
                                const float* __restrict__ Wv, const float* __restrict__ Wo,
                                const float* __restrict__ bq, const float* __restrict__ bk,
                                const float* __restrict__ bv,
                                _Float16* __restrict__ xh, _Float16* __restrict__ Bt,
                                _Float16* __restrict__ WoH,
                                float2* __restrict__ tw, float* __restrict__ bias) {
    const int bid = blockIdx.x;
    const int tid = threadIdx.x;
    if (bid < 16384) {
        int i = (bid * 256 + tid) * 4;
        float4 v = *(const float4*)(x + i);
        half4v h;
        h[0] = (_Float16)v.x; h[1] = (_Float16)v.y;
        h[2] = (_Float16)v.z; h[3] = (_Float16)v.w;
        *(half4v*)(xh + i) = h;
    } else if (bid < 19456) {
        int i = (bid - 16384) * 256 + tid;      // [0, 1536*512)
        int e = i >> 9, k = i & 511;
        int proj = e >> 9, er = e & 511;
        const float* W = (proj == 0) ? Wq : ((proj == 1) ? Wk : Wv);
        Bt[i] = (_Float16)W[er * 512 + k];
    } else if (bid < 20480) {
        int i = (bid - 19456) * 256 + tid;
        WoH[i] = (_Float16)Wo[i];
    } else if (bid < 20496) {
        int p = (bid - 20480) * 256 + tid;      // 4096
        double th = -2.0 * 3.14159265358979323846 * (double)p / 4096.0;
        tw[p] = make_float2((float)cos(th), (float)sin(th));
    } else {
        int i = (bid - 20496) * 256 + tid;      // 1536
        bias[i] = (i < 512) ? bq[i] : ((i < 1024) ? bk[i - 512] : bv[i - 1024]);
    }
}

// ---------- GEMM: C = A * Bt^T (+bias), fp16, K=512, m97-style ----------
template <int MODE>
__global__ __launch_bounds__(256, 4) void gemm_f16_kernel(
    const _Float16* __restrict__ A, const _Float16* __restrict__ Bt,
    const float* __restrict__ bias,
    _Float16* __restrict__ qT, _Float16* __restrict__ kT,
    _Float16* __restrict__ vout, float* __restrict__ Cout)
{
    constexpr int NBLK  = (MODE == 0) ? 12 : 4;
    constexpr int PERXCD = (MODE == 0) ? 384 : 128;   // blocks per XCD slot
    __shared__ _Float16 As[128 * 32];
    __shared__ _Float16 Bs[128 * 32];

    // XCD-aware swizzle: same-mb blocks (sharing the A-tile) colocate on one XCD's L2.
    const int gi = (blockIdx.x & 7) * PERXCD + (blockIdx.x >> 3);
    const int mb = gi / NBLK;
    const int nb = gi - mb * NBLK;
    const int m0 = mb * 128, n0 = nb * 128;
    const int tid = threadIdx.x;
    const int wave = tid >> 6, lane = tid & 63;
    const int wm = (wave & 1) * 64, wn = (wave >> 1) * 64;
    const int lane15 = lane & 15, quad = lane >> 4;
    const int srow = lane >> 2;
    const int scolB = (lane & 3) * 16;

    f32x4 acc[4][4];
#pragma unroll
    for (int mi = 0; mi < 4; mi++)
#pragma unroll
        for (int ni = 0; ni < 4; ni++)
#pragma unroll
            for (int r = 0; r < 4; r++) acc[mi][ni][r] = 0.f;

    for (int kt = 0; kt < 16; kt++) {
        const int kg = kt * 32;
        __syncthreads();
#pragma unroll
        for (int i = 0; i < 2; i++) {
            const int rb = wave * 32 + i * 16;
            const char* ga = (const char*)A  + ((size_t)(m0 + rb + srow)) * 1024 + kg * 2 + scolB;
            const char* gb = (const char*)Bt + ((size_t)(n0 + rb + srow)) * 1024 + kg * 2 + scolB;
            __builtin_amdgcn_global_load_lds((const AS1 void*)ga, (AS3 void*)((char*)As + rb * 64), 16, 0, 0);
            __builtin_amdgcn_global_load_lds((const AS1 void*)gb, (AS3 void*)((char*)Bs + rb * 64), 16, 0, 0);
        }
        __syncthreads();
        half8 af[4], bfr[4];
#pragma unroll
        for (int mi = 0; mi < 4; mi++)
            af[mi] = *(const half8*)((const char*)As + (wm + mi * 16 + lane15) * 64 + quad * 16);
#pragma unroll
        for (int ni = 0; ni < 4; ni++)
            bfr[ni] = *(const half8*)((const char*)Bs + (wn + ni * 16 + lane15) * 64 + quad * 16);
#pragma unroll
        for (int mi = 0; mi < 4; mi++)
#pragma unroll
            for (int ni = 0; ni < 4; ni++)
                acc[mi][ni] = __builtin_amdgcn_mfma_f32_16x16x32_f16(af[mi], bfr[ni], acc[mi][ni], 0, 0, 0);
    }

    if (MODE == 1) {
#pragma unroll
        for (int mi = 0; mi < 4; mi++)
#pragma unroll
            for (int ni = 0; ni < 4; ni++) {
                const int n = n0 + wn + ni * 16 + lane15;
                const float bb = bias[n];
#pragma unroll
                for (int r = 0; r < 4; r++) {
                    const int m = m0 + wm + mi * 16 + quad * 4 + r;
                    Cout[(size_t)m * 512 + n] = acc[mi][ni][r] + bb;
                }
            }
        return;
    }
    const int proj = n0 >> 9;
    if (proj == 2) {   // V -> fp16 (B,H,L,D)
#pragma unroll
        for (int mi = 0; mi < 4; mi++)
#pragma unroll
            for (int ni = 0; ni < 4; ni++) {
                const int n = n0 + wn + ni * 16 + lane15;
                const int er = n - 1024, h = er >> 6, d = er & 63;
                const float bb = bias[n];
#pragma unroll
                for (int r = 0; r < 4; r++) {
                    const int m = m0 + wm + mi * 16 + quad * 4 + r;
                    const int b = m >> 12, l = m & 4095;
                    vout[((size_t)((b * 8 + h) * 4096 + l)) * 64 + d] = (_Float16)(acc[mi][ni][r] + bb);
                }
            }
        return;
    }
    // Q/K: packed-fp16 transposed stores. Lane holds 4 consecutive l (quad*4+r).
    _Float16* dst = (proj == 0) ? qT : kT;
    const int b = m0 >> 12;
    const int lbase = (m0 & 4095) + wm + quad * 4;
#pragma unroll
    for (int mi = 0; mi < 4; mi++)
#pragma unroll
        for (int ni = 0; ni < 4; ni++) {
            const int e = n0 + wn + ni * 16 + lane15;
            const int er = e & 511, h = er >> 6, d = er & 63;
            const float bb = bias[e];
            half4v o;
            o[0] = (_Float16)(acc[mi][ni][0] + bb);
            o[1] = (_Float16)(acc[mi][ni][1] + bb);
            o[2] = (_Float16)(acc[mi][ni][2] + bb);
            o[3] = (_Float16)(acc[mi][ni][3] + bb);
            *(half4v*)(dst + ((size_t)((b * 8 + h) * 64 + d)) * 4096 + lbase + mi * 16) = o;
        }
}

// ---------- FFT: 4096-pt, radix-16 (in-register DFT-16), in-place 32KB LDS ----------
__device__ __forceinline__ float2 cmul(float2 a, float2 b) {
    return make_float2(a.x * b.x - a.y * b.y, a.x * b.y + a.y * b.x);
}
__device__ __forceinline__ float2 cmulc(float2 a, float cr, float ci) {
    return make_float2(a.x * cr - a.y * ci, a.x * ci + a.y * cr);
}
__device__ __forceinline__ int swz(int i) { return i ^ ((i >> 4) & 15); }

// DFT-16 in registers: two radix-4 DIF layers (s=1 then s=4) with W16 twiddles.
// Output natural order.
__device__ __forceinline__ void dft16(float2 x[16]) {
    // W16^e = (cos(-pi e/8), sin(-pi e/8)); e = u*m, u,m in [0,4)
    constexpr float wc[10] = {1.f, 0.92387953f, 0.70710678f, 0.38268343f, 0.f,
                              0.f, -0.70710678f, 0.f, 0.f, -0.92387953f};
    constexpr float wsn[10] = {0.f, -0.38268343f, -0.70710678f, -0.92387953f, -1.f,
                               0.f, -0.70710678f, 0.f, 0.f, 0.38268343f};
    float2 t[16];
#pragma unroll
    for (int u = 0; u < 4; u++) {
        const float2 a = x[u], b = x[u + 4], c = x[u + 8], d = x[u + 12];
        const float2 Ea = make_float2(a.x + c.x, a.y + c.y);
        const float2 Oa = make_float2(a.x - c.x, a.y - c.y);
        const float2 Eb = make_float2(b.x + d.x, b.y + d.y);
        const float2 Ob = make_float2(b.x - d.x, b.y - d.y);
        const float2 y0 = make_float2(Ea.x + Eb.x, Ea.y + Eb.y);
        const float2 y1 = make_float2(Oa.x + Ob.y, Oa.y - Ob.x);   // Oa - i*Ob
        const float2 y2 = make_float2(Ea.x - Eb.x, Ea.y - Eb.y);
        const float2 y3 = make_float2(Oa.x - Ob.y, Oa.y + Ob.x);   // Oa + i*Ob
        t[4 * u + 0] = y0;
        t[4 * u + 1] = cmulc(y1, wc[u * 1], wsn[u * 1]);
        t[4 * u + 2] = cmulc(y2, wc[u * 2], wsn[u * 2]);
        t[4 * u + 3] = cmulc(y3, wc[u * 3], wsn[u * 3]);
    }
#pragma unroll
    for (int v = 0; v < 4; v++) {
        const float2 a = t[v], b = t[v + 4], c = t[v + 8], d = t[v + 12];
        const float2 Ea = make_float2(a.x + c.x, a.y + c.y);
        const float2 Oa = make_float2(a.x - c.x, a.y - c.y);
        const float2 Eb = make_float2(b.x + d.x, b.y + d.y);
        const float2 Ob = make_float2(b.x - d.x, b.y - d.y);
        x[v]      = make_float2(Ea.x + Eb.x, Ea.y + Eb.y);
        x[v + 4]  = make_float2(Oa.x + Ob.y, Oa.y - Ob.x);
        x[v + 8]  = make_float2(Ea.x - Eb.x, Ea.y - Eb.y);
        x[v + 12] = make_float2(Oa.x - Ob.y, Oa.y + Ob.x);
    }
}

// In-place 4096-pt forward FFT over swizzled buf. Entry sync covers caller's fill;
// exits synced. 3 stages s=1,16,256; twiddle W_4096^{s*p*m} from 4096-entry table.
__device__ __forceinline__ void fft4096_r16(float2* buf, const float2* __restrict__ tw,
                                            int tid) {
    float2 x[16];
    // ---- stage A: s=1, q=0, p=tid ----
    __syncthreads();
#pragma unroll
    for (int j = 0; j < 16; j++) x[j] = buf[swz(tid + 256 * j)];
    __syncthreads();
    dft16(x);
    buf[swz(16 * tid)] = x[0];
#pragma unroll
    for (int m = 1; m < 16; m++) buf[swz(16 * tid + m)] = cmul(x[m], tw[tid * m]);
    __syncthreads();
    // ---- stage B: s=16, q=tid&15, p=tid>>4 ----
#pragma unroll
    for (int j = 0; j < 16; j++) x[j] = buf[swz(tid + 256 * j)];
    __syncthreads();
    dft16(x);
    {
        const int q = tid & 15, p = tid >> 4;
        const int base = q + 256 * p;
        buf[swz(base)] = x[0];
#pragma unroll
        for (int m = 1; m < 16; m++)
            buf[swz(base + 16 * m)] = cmul(x[m], tw[(p * m) << 4]);
    }
    __syncthreads();
    // ---- stage C: s=256, q=tid, p=0 (no twiddle) ----
#pragma unroll
    for (int j = 0; j < 16; j++) x[j] = buf[swz(tid + 256 * j)];
    __syncthreads();
    dft16(x);
#pragma unroll
    for (int m = 0; m < 16; m++) buf[swz(tid + 256 * m)] = x[m];
    __syncthreads();
}

// per block: one (b,h), 4 d's. Packed FFT(q + i k), accumulate S=Q*conj(K), write partial.
// NOTE: plain launch_bounds — round 4's (256,4) capped VGPRs at 64 and the sx/sy+x[16]
// live set (~150) spilled to scratch: FETCH 33->272 MB, dur 105->157 us. Let the
// allocator take ~150-180 VGPRs; 32 KB LDS still gives ~3 blocks/CU.
__global__ __launch_bounds__(256) void fft_partial_kernel(
    const _Float16* __restrict__ qT, const _Float16* __restrict__ kT,
    const float2* __restrict__ tw, float2* __restrict__ spec)
{
    __shared__ float2 buf[4096];
    const int tid = threadIdx.x;
    const int bh = blockIdx.x >> 4, chunk = blockIdx.x & 15;
    float sx[16], sy[16];
#pragma unroll
    for (int i = 0; i < 16; i++) { sx[i] = 0.f; sy[i] = 0.f; }
    const _Float16* qb = qT + (size_t)bh * 64 * 4096;
    const _Float16* kb = kT + (size_t)bh * 64 * 4096;
    for (int dd = 0; dd < 4; dd++) {
        const int d = chunk * 4 + dd;
#pragma unroll
        for (int i = 0; i < 2; i++) {
            const int t0 = 2048 * i + tid * 8;
            const half8 fq = *(const half8*)(qb + d * 4096 + t0);
            const half8 fk = *(const half8*)(kb + d * 4096 + t0);
#pragma unroll
            for (int j = 0; j < 8; j++)
                buf[swz(t0 + j)] = make_float2((float)fq[j], (float)fk[j]);
        }
        fft4096_r16(buf, tw, tid);
        // unpack packed transforms; accumulate S = Q * conj(K)
#pragma unroll
        for (int i = 0; i < 16; i++) {
            const int f = tid + 256 * i;
            const float2 Zf = buf[swz(f)];
            const float2 Zm = buf[swz((4096 - f) & 4095)];
            const float Qr  = 0.5f * (Zf.x + Zm.x);
            const float Qi  = 0.5f * (Zf.y - Zm.y);
            const float cKr = 0.5f * (Zf.y + Zm.y);
            const float cKi = 0.5f * (Zf.x - Zm.x);
            sx[i] += Qr * cKr - Qi * cKi;
            sy[i] += Qr * cKi + Qi * cKr;
        }
        __syncthreads();   // protect buf before next fill
    }
    float2* out = spec + (size_t)blockIdx.x * 4096;
#pragma unroll
    for (int i = 0; i < 16; i++) out[tid + 256 * i] = make_float2(sx[i], sy[i]);
}

// per block: one (b,h). Sum 16 partials, corr = Re(FFT(conj(S))); top-8 + softmax.
__global__ __launch_bounds__(256) void reduce_topk_kernel(
    const float2* __restrict__ spec, const float2* __restrict__ tw,
    int* __restrict__ top_idx, float* __restrict__ top_w)
{
    __shared__ float2 buf[4096];
    __shared__ float wv[4];
    __shared__ int wi[4];
    const int tid = threadIdx.x;
    const int bh = blockIdx.x;
#pragma unroll
    for (int i = 0; i < 16; i++) {
        const int f = tid + 256 * i;
        float sr = 0.f, si = 0.f;
        for (int c = 0; c < 16; c++) {
            const float2 v = spec[((size_t)(bh * 16 + c)) * 4096 + f];
            sr += v.x; si += v.y;
        }
        buf[swz(f)] = make_float2(sr, -si);   // conj
    }
    fft4096_r16(buf, tw, tid);
    // buf[tau].x ~ corr(tau) (unscaled). Top-8, lower-index tie-break.
    float vals[8]; int idxs[8];
    for (int k = 0; k < 8; k++) {
        float best = -3.0e38f; int bi = 0;
#pragma unroll
        for (int i = 0; i < 16; i++) {
            const int f = tid + 256 * i;
            const float c = buf[swz(f)].x;
            if (c > best) { best = c; bi = f; }
        }
#pragma unroll
        for (int off = 32; off > 0; off >>= 1) {
            const float ov = __shfl_down(best, off);
            const int oi = __shfl_down(bi, off);
            if (ov > best || (ov == best && oi < bi)) { best = ov; bi = oi; }
        }
        if ((tid & 63) == 0) { wv[tid >> 6] = best; wi[tid >> 6] = bi; }
        __syncthreads();
        if (tid == 0) {
            best = wv[0]; bi = wi[0];
            for (int w = 1; w < 4; w++) {
                if (wv[w] > best || (wv[w] == best && wi[w] < bi)) { best = wv[w]; bi = wi[w]; }
            }
            vals[k] = best; idxs[k] = bi;
            buf[swz(bi)].x = -3.4e38f;
        }
        __syncthreads();
    }
    if (tid == 0) {
        const float scale = 1.f / (4096.f * 64.f);
        float e[8], s = 0.f;
        const float mx = vals[0] * scale;
        for (int k = 0; k < 8; k++) { e[k] = __expf(vals[k] * scale - mx); s += e[k]; }
        for (int k = 0; k < 8; k++) {
            top_w[bh * 8 + k] = e[k] / s;
            top_idx[bh * 8 + k] = idxs[k];
        }
    }
}

// ---------- gather: out_pre[b,l,h*64+d] = sum_k w_k * v[b,h,(l+idx_k)%L,d] ----------
__global__ __launch_bounds__(256) void gather_kernel(
    const half2v* __restrict__ v2, const int* __restrict__ top_idx,
    const float* __restrict__ top_w, half2v* __restrict__ out2)
{
    const int seq = blockIdx.x;           // 32768
    const int bh = seq >> 9;
    const int lgrp = seq & 511;
    const int b = bh >> 3, h = bh & 7;
    const int tid = threadIdx.x;
    const int l = lgrp * 8 + (tid >> 5);
    const int d2 = tid & 31;              // half2 index
    int idx[8]; float w[8];
#pragma unroll
    for (int k = 0; k < 8; k++) { idx[k] = top_idx[bh * 8 + k]; w[k] = top_w[bh * 8 + k]; }
    const half2v* vb = v2 + (size_t)bh * 4096 * 32;
    float a0 = 0.f, a1 = 0.f;
#pragma unroll
    for (int k = 0; k < 8; k++) {
        const int ls = (l + idx[k]) & 4095;
        const half2v pv = vb[ls * 32 + d2];
        a0 += w[k] * (float)pv[0];
        a1 += w[k] * (float)pv[1];
    }
    half2v o; o[0] = (_Float16)a0; o[1] = (_Float16)a1;
    out2[((size_t)(b * 4096 + l)) * 256 + h * 32 + d2] = o;
}

// ---------- host ----------
extern "C" void kernel_launch(void* const* d_in, const int* in_sizes, int n_in,
                              void* d_out, int out_size, void* d_ws, size_t ws_size,
                              hipStream_t stream) {
    (void)in_sizes; (void)n_in; (void)out_size; (void)ws_size;
    const float* x  = (const float*)d_in[0];
    const float* Wq = (const float*)d_in[1];
    const float* bq = (const float*)d_in[2];
    const float* Wk = (const float*)d_in[3];
    const float* bk = (const float*)d_in[4];
    const float* Wv = (const float*)d_in[5];
    const float* bv = (const float*)d_in[6];
    const float* Wo = (const float*)d_in[7];
    const float* bo = (const float*)d_in[8];
    float* out = (float*)d_out;

    char* ws = (char*)d_ws;
    size_t off = 0;
    auto alloc = [&](size_t bytes) -> void* {
        void* p = ws + off; off += (bytes + 255) & ~(size_t)255; return p;
    };
    _Float16* xh   = (_Float16*)alloc(33554432);   // 32768x512 fp16
    _Float16* qT   = (_Float16*)alloc(33554432);   // (B,H,D,L) fp16
    _Float16* kT   = (_Float16*)alloc(33554432);
    _Float16* vbuf = (_Float16*)alloc(33554432);   // (B,H,L,D) fp16
    float2* spec   = (float2*)alloc(33554432);     // 1024 x 4096 float2
    _Float16* BtH  = (_Float16*)alloc(1572864);    // 1536x512 fp16
    _Float16* WoH  = (_Float16*)alloc(524288);     // 512x512 fp16
    float* biasQKV = (float*)alloc(6144);          // 1536 fp32
    float2* tw     = (float2*)alloc(32768);        // 4096 twiddles
    int*   top_idx = (int*)alloc(2048);
    float* top_w   = (float*)alloc(2048);
    _Float16* out_pre = xh;                        // alias: xh dead after GEMM1

    prep_all_kernel<<<20502, 256, 0, stream>>>(x, Wq, Wk, Wv, Wo, bq, bk, bv,
                                               xh, BtH, WoH, tw, biasQKV);
    gemm_f16_kernel<0><<<3072, 256, 0, stream>>>(xh, BtH, biasQKV, qT, kT, vbuf, nullptr);
    fft_partial_kernel<<<1024, 256, 0, stream>>>(qT, kT, tw, spec);
    reduce_topk_kernel<<<64, 256, 0, stream>>>(spec, tw, top_idx, top_w);
    gather_kernel<<<32768, 256, 0, stream>>>((const half2v*)vbuf, top_idx, top_w,
                                             (half2v*)out_pre);
    gemm_f16_kernel<1><<<1024, 256, 0, stream>>>(out_pre, WoH, bo, nullptr, nullptr, nullptr, out);
}